// Round 1
// baseline (210.359 us; speedup 1.0000x reference)
//
#include <hip/hip_runtime.h>
#include <math.h>

// GHM-C loss: two-pass.
// Pass 1: grid-stride over all N*C logits, per-thread nested accumulators
//   S_k = sum of bce over elements with bin >= k (k=0..9)
//   C_k = count of elements with bin >= k        (k=1..9; C_0 = N*C known)
// using s = (label==col) ? -p : p, so g = sigmoid(s), bce = softplus(s),
// and bin >= k  <=>  s >= logit(k/10). Per-block partials -> d_ws (no atomics,
// no zero-init needed since each block writes its own slot).
// Pass 2: single block reduces partials, differences nested sums into per-bin
// values, computes loss = sum_b binsum_b / (bincnt_b * n_nonempty).

#define PASS1_BLOCK 256

__device__ __forceinline__ void wave_red(float& v) {
#pragma unroll
    for (int off = 32; off > 0; off >>= 1) v += __shfl_down(v, off, 64);
}
__device__ __forceinline__ void wave_red(unsigned& v) {
#pragma unroll
    for (int off = 32; off > 0; off >>= 1) v += __shfl_down(v, off, 64);
}

__device__ __forceinline__ void update_elem(float p, bool isT,
                                            float (&S)[10], unsigned (&Cc)[9]) {
    // logit(k/10), k=1..9
    const float T[9] = {-2.1972246f, -1.3862944f, -0.84729786f, -0.40546511f,
                        0.0f, 0.40546511f, 0.84729786f, 1.3862944f, 2.1972246f};
    float s = isT ? -p : p;
    float a = fabsf(s);
    float en = __expf(-a);                    // exp(-|s|) in (0,1]
    float bce = fmaxf(s, 0.0f) + __logf(1.0f + en);  // softplus(s), stable
    S[0] += bce;
#pragma unroll
    for (int q = 0; q < 9; ++q) {
        bool b = (s >= T[q]);
        S[q + 1] += b ? bce : 0.0f;
        Cc[q] += b ? 1u : 0u;
    }
}

__global__ __launch_bounds__(PASS1_BLOCK) void ghmc_pass1(
    const float* __restrict__ pred, const int* __restrict__ target,
    float* __restrict__ blk_S, unsigned* __restrict__ blk_C,
    unsigned total4, unsigned totalNC, int C, int shift) {
    float S[10];
    unsigned Cc[9];
#pragma unroll
    for (int i = 0; i < 10; ++i) S[i] = 0.0f;
#pragma unroll
    for (int i = 0; i < 9; ++i) Cc[i] = 0u;

    unsigned tid = blockIdx.x * blockDim.x + threadIdx.x;
    unsigned stride = gridDim.x * blockDim.x;
    const float4* p4 = (const float4*)pred;
    unsigned cmask = (unsigned)C - 1u;

    for (unsigned v = tid; v < total4; v += stride) {
        unsigned e = v << 2;
        unsigned row, col;
        if (shift >= 0) {
            row = e >> shift;
            col = e & cmask;
        } else {
            row = e / (unsigned)C;
            col = e - row * (unsigned)C;
        }
        float4 p = p4[v];
        int tj = target[row];  // wave-uniform in the common layout (broadcast)
        update_elem(p.x, tj == (int)(col + 0u), S, Cc);
        update_elem(p.y, tj == (int)(col + 1u), S, Cc);
        update_elem(p.z, tj == (int)(col + 2u), S, Cc);
        update_elem(p.w, tj == (int)(col + 3u), S, Cc);
    }

    // rare tail (NC not divisible by 4) handled by global thread 0
    if (tid == 0) {
        for (unsigned e = total4 << 2; e < totalNC; ++e) {
            unsigned row, col;
            if (shift >= 0) {
                row = e >> shift;
                col = e & cmask;
            } else {
                row = e / (unsigned)C;
                col = e - row * (unsigned)C;
            }
            update_elem(pred[e], target[row] == (int)col, S, Cc);
        }
    }

#pragma unroll
    for (int i = 0; i < 10; ++i) wave_red(S[i]);
#pragma unroll
    for (int i = 0; i < 9; ++i) wave_red(Cc[i]);

    __shared__ float sS[PASS1_BLOCK / 64][10];
    __shared__ unsigned sC[PASS1_BLOCK / 64][9];
    int wid = threadIdx.x >> 6;
    int lane = threadIdx.x & 63;
    if (lane == 0) {
        for (int i = 0; i < 10; ++i) sS[wid][i] = S[i];
        for (int i = 0; i < 9; ++i) sC[wid][i] = Cc[i];
    }
    __syncthreads();
    if (threadIdx.x == 0) {
        const int nw = PASS1_BLOCK / 64;
        for (int i = 0; i < 10; ++i) {
            float acc = 0.0f;
            for (int w = 0; w < nw; ++w) acc += sS[w][i];
            blk_S[blockIdx.x * 10 + i] = acc;
        }
        for (int i = 0; i < 9; ++i) {
            unsigned acc = 0u;
            for (int w = 0; w < nw; ++w) acc += sC[w][i];
            blk_C[blockIdx.x * 9 + i] = acc;
        }
    }
}

__global__ __launch_bounds__(256) void ghmc_pass2(
    const float* __restrict__ blk_S, const unsigned* __restrict__ blk_C,
    float* __restrict__ out, int nblocks, unsigned totalNC) {
    float S[10];
    unsigned Cc[9];
#pragma unroll
    for (int i = 0; i < 10; ++i) S[i] = 0.0f;
#pragma unroll
    for (int i = 0; i < 9; ++i) Cc[i] = 0u;

    for (int b = threadIdx.x; b < nblocks; b += blockDim.x) {
        for (int i = 0; i < 10; ++i) S[i] += blk_S[b * 10 + i];
        for (int i = 0; i < 9; ++i) Cc[i] += blk_C[b * 9 + i];
    }

#pragma unroll
    for (int i = 0; i < 10; ++i) wave_red(S[i]);
#pragma unroll
    for (int i = 0; i < 9; ++i) wave_red(Cc[i]);

    __shared__ float sS[4][10];
    __shared__ unsigned sC[4][9];
    int wid = threadIdx.x >> 6;
    int lane = threadIdx.x & 63;
    if (lane == 0) {
        for (int i = 0; i < 10; ++i) sS[wid][i] = S[i];
        for (int i = 0; i < 9; ++i) sC[wid][i] = Cc[i];
    }
    __syncthreads();
    if (threadIdx.x == 0) {
        float Sv[11];
        unsigned Cv[11];
        for (int i = 0; i < 10; ++i) {
            float a = 0.0f;
            for (int w = 0; w < 4; ++w) a += sS[w][i];
            Sv[i] = a;
        }
        Sv[10] = 0.0f;
        Cv[0] = totalNC;
        for (int i = 1; i < 10; ++i) {
            unsigned a = 0u;
            for (int w = 0; w < 4; ++w) a += sC[w][i - 1];
            Cv[i] = a;
        }
        Cv[10] = 0u;

        int nonempty = 0;
        for (int b = 0; b < 10; ++b)
            if (Cv[b] - Cv[b + 1] > 0u) nonempty++;
        float n = fmaxf((float)nonempty, 1.0f);

        float loss = 0.0f;
        for (int b = 0; b < 10; ++b) {
            unsigned cnt = Cv[b] - Cv[b + 1];
            if (cnt > 0u) {
                float bs = Sv[b] - Sv[b + 1];
                loss += bs / ((float)cnt * n);
            }
        }
        out[0] = loss;  // LOSS_WEIGHT = 1.0
    }
}

extern "C" void kernel_launch(void* const* d_in, const int* in_sizes, int n_in,
                              void* d_out, int out_size, void* d_ws, size_t ws_size,
                              hipStream_t stream) {
    const float* pred = (const float*)d_in[0];
    const int* target = (const int*)d_in[1];
    int NC = in_sizes[0];
    int N = in_sizes[1];
    int C = NC / N;
    unsigned total4 = (unsigned)(NC / 4);
    int shift = ((C & (C - 1)) == 0) ? (__builtin_ctz((unsigned)C) + 0) : -1;
    // note: row = e >> log2(C); e = element index, so shift = log2(C)
    // (col = e & (C-1) only valid for pow2 C)

    int blocks = 1024;
    size_t per_block = (10 + 9) * sizeof(float);
    if (ws_size < (size_t)blocks * per_block) {
        size_t maxb = ws_size / per_block;
        blocks = (int)(maxb > 0 ? maxb : 1);
    }

    float* blk_S = (float*)d_ws;
    unsigned* blk_C = (unsigned*)((char*)d_ws + (size_t)blocks * 10 * sizeof(float));

    ghmc_pass1<<<blocks, PASS1_BLOCK, 0, stream>>>(pred, target, blk_S, blk_C,
                                                   total4, (unsigned)NC, C, shift);
    ghmc_pass2<<<1, 256, 0, stream>>>(blk_S, blk_C, (float*)d_out, blocks,
                                      (unsigned)NC);
}